// Round 11
// baseline (225.624 us; speedup 1.0000x reference)
//
#include <hip/hip_runtime.h>
#include <hip/hip_cooperative_groups.h>

namespace cg = cooperative_groups;

#define T_DIM 1024
#define D_DIM 64
#define WIN   128
#define TILE  64       // output rows per block
#define KROWS 192      // staged rows = TILE + WIN
#define NT    12       // KROWS/16 col-tiles
#define NTHR  256      // 4 waves
#define NBLK  512      // 32 (b,h) * 16 tiles = 2 blocks/CU exactly
#define NBH   32

typedef __attribute__((ext_vector_type(8))) short short8;
typedef __attribute__((ext_vector_type(4))) float f32x4;

__device__ __forceinline__ unsigned int pack2bf(float a, float b) {
  unsigned int ua = __float_as_uint(a);
  unsigned int ub = __float_as_uint(b);
  ua = (ua + 0x7fffu + ((ua >> 16) & 1u)) >> 16;   // RNE f32->bf16
  ub = (ub + 0x7fffu + ((ub >> 16) & 1u)) >> 16;
  return ua | (ub << 16);
}

// ---------------------------------------------------------------------------
// Fused: stage U once, MFMA once, grid.sync for the global invden sum,
// softmax on retained accumulators, disjoint zero + band f32x4 stores.
// ---------------------------------------------------------------------------
__global__ __launch_bounds__(NTHR, 2)
void fused_kernel(const float* __restrict__ E, float* __restrict__ out,
                  float* __restrict__ partials)
{
  __shared__ uint4 Kb4[KROWS * 8];           // 24 KB, swizzled 16B units
  __shared__ float wpart[4];
  __shared__ float s_rsum;

  const int tid = threadIdx.x, lane = tid & 63, wv = tid >> 6;
  const int blk = blockIdx.x, bh = blk >> 4, base = (blk & 15) * TILE;
  const float* Ebh = E + (size_t)bh * (T_DIM * D_DIM);

  // ---- stage rows [base-128, base+63] normalized (U=E/|E|) bf16, swizzled --
  #pragma unroll
  for (int it = 0; it < (KROWS * 8) / NTHR; ++it) {   // 6 iters
    int u = tid + it * NTHR;
    int r = u >> 3, c = u & 7;
    int gr = base - WIN + r;
    uint4 w = make_uint4(0u, 0u, 0u, 0u);
    if (gr >= 0) {
      const float4 f0 = *(const float4*)(Ebh + gr * D_DIM + c * 8);
      const float4 f1 = *(const float4*)(Ebh + gr * D_DIM + c * 8 + 4);
      float ss = f0.x*f0.x + f0.y*f0.y + f0.z*f0.z + f0.w*f0.w
               + f1.x*f1.x + f1.y*f1.y + f1.z*f1.z + f1.w*f1.w;
      ss += __shfl_xor(ss, 1);
      ss += __shfl_xor(ss, 2);
      ss += __shfl_xor(ss, 4);
      float rn = rsqrtf(ss + 1e-16f);
      w.x = pack2bf(f0.x*rn, f0.y*rn); w.y = pack2bf(f0.z*rn, f0.w*rn);
      w.z = pack2bf(f1.x*rn, f1.y*rn); w.w = pack2bf(f1.z*rn, f1.w*rn);
    }
    Kb4[(r << 3) + (c ^ (r & 7))] = w;
  }
  __syncthreads();

  // ---- zero pass: thread owns uint4-col q=tid; drains under MFMA ----------
  {
    const f32x4 z = {0.f, 0.f, 0.f, 0.f};
    f32x4* outq = (f32x4*)out + ((size_t)bh * T_DIM + base) * (T_DIM / 4);
    const int q = tid;
    #pragma unroll 4
    for (int r = 0; r < TILE; ++r) {
      int i = base + r;
      int q0 = (i >= WIN) ? ((i - WIN) >> 2) : 0;
      int q1 = i >> 2;
      if (q < q0 || q > q1)
        __builtin_nontemporal_store(z, &outq[r * (T_DIM / 4) + q]);
    }
  }

  // ---- MFMA: swapped operands (D = K.Q^T) -> lane holds 4 consecutive j ---
  const short8* KbF = (const short8*)Kb4;
  const int mrow = lane & 15, kg = lane >> 4;
  const int i_local = wv * 16 + mrow;
  const int i_g = base + i_local;

  const int qr = WIN + i_local;              // Q fragment (D cols = i)
  short8 b0 = KbF[(qr << 3) + (kg ^ (qr & 7))];
  short8 b1 = KbF[(qr << 3) + ((kg + 4) ^ (qr & 7))];

  f32x4 acc[NT];
  float sacc = 0.f;
  #pragma unroll
  for (int t = 0; t < NT; ++t) {
    if (t < wv || t > wv + 8) continue;      // no valid (i,j) outside
    int br = t * 16 + mrow;                  // K rows (D rows = j)
    short8 a0 = KbF[(br << 3) + (kg ^ (br & 7))];
    short8 a1 = KbF[(br << 3) + ((kg + 4) ^ (br & 7))];
    f32x4 ca = {0.f, 0.f, 0.f, 0.f};
    ca = __builtin_amdgcn_mfma_f32_16x16x32_bf16(a0, b0, ca, 0, 0, 0);
    ca = __builtin_amdgcn_mfma_f32_16x16x32_bf16(a1, b1, ca, 0, 0, 0);
    acc[t] = ca;                             // reg g: rj = t*16+kg*4+g, col i
    #pragma unroll
    for (int g = 0; g < 4; ++g) {
      int rj = t * 16 + kg * 4 + g;
      bool valid = (rj >= i_local) && (rj <= i_local + WIN)
                && (base - WIN + rj >= 0);
      sacc += valid ? ca[g] : 0.f;
    }
  }
  sacc += __shfl_xor(sacc, 16);
  sacc += __shfl_xor(sacc, 32);              // S_i in all lanes
  const float invden = 2048.f / (2048.f + sacc);      // 1/denom (2T = 2048)

  // per-block partial of sum(invden): one contribution per row (kg==0 lanes)
  float v = (kg == 0) ? invden : 0.f;
  #pragma unroll
  for (int m = 1; m < 64; m <<= 1) v += __shfl_xor(v, m);
  if (lane == 0) wpart[wv] = v;
  __syncthreads();
  if (tid == 0) partials[blk] = wpart[0] + wpart[1] + wpart[2] + wpart[3];

  cg::this_grid().sync();

  // rsum = 1 / sum of this bh's 16 partials
  if (tid < 16) {
    float p = partials[(bh << 4) + tid];
    #pragma unroll
    for (int m = 1; m < 16; m <<= 1) p += __shfl_xor(p, m);
    if (tid == 0) s_rsum = 1.0f / p;
  }
  __syncthreads();

  const float fh = 0.5f * invden * s_rsum;   // 0.5 * fitness_i

  // ---- masked value + in-register softmax (reduce over kg: 2 shfls) -------
  float mx = -1e30f, esum = 0.f;
  #pragma unroll
  for (int t = 0; t < NT; ++t) {
    if (t < wv || t > wv + 8) continue;
    #pragma unroll
    for (int g = 0; g < 4; ++g) {
      int rj = t * 16 + kg * 4 + g;
      bool valid = (rj >= i_local) && (rj <= i_local + WIN)
                && (base - WIN + rj >= 0);
      float val = valid ? fh * acc[t][g] + fh : -1e30f;  // (corr+1)*0.5*fit
      acc[t][g] = val;
      mx = fmaxf(mx, val);
    }
  }
  mx = fmaxf(mx, __shfl_xor(mx, 16));
  mx = fmaxf(mx, __shfl_xor(mx, 32));
  #pragma unroll
  for (int t = 0; t < NT; ++t) {
    if (t < wv || t > wv + 8) continue;
    #pragma unroll
    for (int g = 0; g < 4; ++g) {
      float e = __expf(acc[t][g] - mx);      // masked -> 0
      acc[t][g] = e;
      esum += e;
    }
  }
  esum += __shfl_xor(esum, 16);
  esum += __shfl_xor(esum, 32);
  const float rinv = 1.0f / esum;

  // ---- band cover stores: f32x4 chunks within [jlo, jhi] (uint4-aligned) --
  const int jlo = (i_g >= WIN) ? ((i_g - WIN) & ~3) : 0;
  const int jhi = (i_g & ~3) + 3;
  float* outrow = out + ((size_t)bh * T_DIM + i_g) * T_DIM;
  #pragma unroll
  for (int t = 0; t < NT; ++t) {
    if (t < wv || t > wv + 8) continue;
    int jb = base - WIN + t * 16 + kg * 4;   // 4-aligned global j of chunk
    if (jb >= jlo && jb + 3 <= jhi) {
      f32x4 val = {acc[t][0] * rinv, acc[t][1] * rinv,
                   acc[t][2] * rinv, acc[t][3] * rinv};
      __builtin_nontemporal_store(val, (f32x4*)(outrow + jb));
    }
  }
}

extern "C" void kernel_launch(void* const* d_in, const int* in_sizes, int n_in,
                              void* d_out, int out_size, void* d_ws, size_t ws_size,
                              hipStream_t stream) {
  const float* E = (const float*)d_in[0];
  float* out = (float*)d_out;
  float* partials = (float*)d_ws;            // 512 floats used
  void* args[] = { (void*)&E, (void*)&out, (void*)&partials };
  hipLaunchCooperativeKernel((const void*)fused_kernel, dim3(NBLK), dim3(NTHR),
                             args, 0, stream);
}

// Round 12
// 173.331 us; speedup vs baseline: 1.3017x; 1.3017x over previous
//
#include <hip/hip_runtime.h>

#define T_DIM 1024
#define D_DIM 64
#define WIN   128
#define TILE  64       // output rows per block
#define KROWS 192      // staged rows = TILE + WIN
#define NT    12       // KROWS/16 col-tiles
#define NTHR  256      // 4 waves
#define NBLK  512      // 32 (b,h) * 16 tiles = 2 blocks/CU exactly (co-resident)
#define NBH   32

typedef __attribute__((ext_vector_type(8))) short short8;
typedef __attribute__((ext_vector_type(4))) float f32x4;

__device__ __forceinline__ unsigned int pack2bf(float a, float b) {
  unsigned int ua = __float_as_uint(a);
  unsigned int ub = __float_as_uint(b);
  ua = (ua + 0x7fffu + ((ua >> 16) & 1u)) >> 16;   // RNE f32->bf16
  ub = (ub + 0x7fffu + ((ub >> 16) & 1u)) >> 16;
  return ua | (ub << 16);
}

// ---------------------------------------------------------------------------
// Fused, non-cooperative: stage U once, MFMA once, per-bh 16-block flag sync
// (all 512 blocks co-resident at 2/CU), softmax on retained accumulators,
// band f32x4 stores, zero stores issued last (fire-and-forget).
// ---------------------------------------------------------------------------
__global__ __launch_bounds__(NTHR, 2)
void fused_kernel(const float* __restrict__ E, float* __restrict__ out,
                  float* __restrict__ partials, unsigned int* __restrict__ flags)
{
  __shared__ uint4 Kb4[KROWS * 8];           // 24 KB, swizzled 16B units
  __shared__ float wpart[4];
  __shared__ float s_rsum;

  const int tid = threadIdx.x, lane = tid & 63, wv = tid >> 6;
  const int blk = blockIdx.x, bh = blk >> 4, base = (blk & 15) * TILE;
  const float* Ebh = E + (size_t)bh * (T_DIM * D_DIM);

  // ---- stage rows [base-128, base+63] normalized (U=E/|E|) bf16, swizzled --
  #pragma unroll
  for (int it = 0; it < (KROWS * 8) / NTHR; ++it) {   // 6 iters
    int u = tid + it * NTHR;
    int r = u >> 3, c = u & 7;
    int gr = base - WIN + r;
    uint4 w = make_uint4(0u, 0u, 0u, 0u);
    if (gr >= 0) {
      const float4 f0 = *(const float4*)(Ebh + gr * D_DIM + c * 8);
      const float4 f1 = *(const float4*)(Ebh + gr * D_DIM + c * 8 + 4);
      float ss = f0.x*f0.x + f0.y*f0.y + f0.z*f0.z + f0.w*f0.w
               + f1.x*f1.x + f1.y*f1.y + f1.z*f1.z + f1.w*f1.w;
      ss += __shfl_xor(ss, 1);
      ss += __shfl_xor(ss, 2);
      ss += __shfl_xor(ss, 4);
      float rn = rsqrtf(ss + 1e-16f);
      w.x = pack2bf(f0.x*rn, f0.y*rn); w.y = pack2bf(f0.z*rn, f0.w*rn);
      w.z = pack2bf(f1.x*rn, f1.y*rn); w.w = pack2bf(f1.z*rn, f1.w*rn);
    }
    Kb4[(r << 3) + (c ^ (r & 7))] = w;
  }
  __syncthreads();

  // ---- MFMA: swapped operands (D = K.Q^T) -> lane holds 4 consecutive j ---
  const short8* KbF = (const short8*)Kb4;
  const int mrow = lane & 15, kg = lane >> 4;
  const int i_local = wv * 16 + mrow;
  const int i_g = base + i_local;

  const int qr = WIN + i_local;              // Q fragment (D cols = i)
  short8 b0 = KbF[(qr << 3) + (kg ^ (qr & 7))];
  short8 b1 = KbF[(qr << 3) + ((kg + 4) ^ (qr & 7))];

  f32x4 acc[NT];
  float sacc = 0.f;
  #pragma unroll
  for (int t = 0; t < NT; ++t) {
    if (t < wv || t > wv + 8) continue;      // no valid (i,j) outside
    int br = t * 16 + mrow;                  // K rows (D rows = j)
    short8 a0 = KbF[(br << 3) + (kg ^ (br & 7))];
    short8 a1 = KbF[(br << 3) + ((kg + 4) ^ (br & 7))];
    f32x4 ca = {0.f, 0.f, 0.f, 0.f};
    ca = __builtin_amdgcn_mfma_f32_16x16x32_bf16(a0, b0, ca, 0, 0, 0);
    ca = __builtin_amdgcn_mfma_f32_16x16x32_bf16(a1, b1, ca, 0, 0, 0);
    acc[t] = ca;                             // reg g: rj = t*16+kg*4+g, col i
    #pragma unroll
    for (int g = 0; g < 4; ++g) {
      int rj = t * 16 + kg * 4 + g;
      bool valid = (rj >= i_local) && (rj <= i_local + WIN)
                && (base - WIN + rj >= 0);
      sacc += valid ? ca[g] : 0.f;
    }
  }
  sacc += __shfl_xor(sacc, 16);
  sacc += __shfl_xor(sacc, 32);              // S_i in all lanes
  const float invden = 2048.f / (2048.f + sacc);      // 1/denom (2T = 2048)

  // ---- publish per-block partial of sum(invden) ---------------------------
  float v = (kg == 0) ? invden : 0.f;        // one contribution per row
  #pragma unroll
  for (int m = 1; m < 64; m <<= 1) v += __shfl_xor(v, m);
  if (lane == 0) wpart[wv] = v;
  __syncthreads();
  if (tid == 0) {
    float psum = wpart[0] + wpart[1] + wpart[2] + wpart[3];
    __hip_atomic_store(&partials[blk], psum, __ATOMIC_RELAXED,
                       __HIP_MEMORY_SCOPE_AGENT);
    __hip_atomic_store(&flags[blk], 1u, __ATOMIC_RELEASE,
                       __HIP_MEMORY_SCOPE_AGENT);
  }

  // ---- 16-block scoped sync: poll sibling flags (all co-resident) ---------
  if (tid < 16) {
    const int sib = (bh << 4) + tid;
    while (__hip_atomic_load(&flags[sib], __ATOMIC_ACQUIRE,
                             __HIP_MEMORY_SCOPE_AGENT) != 1u)
      __builtin_amdgcn_s_sleep(1);
    float p = __hip_atomic_load(&partials[sib], __ATOMIC_RELAXED,
                                __HIP_MEMORY_SCOPE_AGENT);
    #pragma unroll
    for (int m = 1; m < 16; m <<= 1) p += __shfl_xor(p, m);
    if (tid == 0) s_rsum = 1.0f / p;
  }
  __syncthreads();

  const float fh = 0.5f * invden * s_rsum;   // 0.5 * fitness_i

  // ---- masked value + in-register softmax (reduce over kg: 2 shfls) -------
  float mx = -1e30f, esum = 0.f;
  #pragma unroll
  for (int t = 0; t < NT; ++t) {
    if (t < wv || t > wv + 8) continue;
    #pragma unroll
    for (int g = 0; g < 4; ++g) {
      int rj = t * 16 + kg * 4 + g;
      bool valid = (rj >= i_local) && (rj <= i_local + WIN)
                && (base - WIN + rj >= 0);
      float val = valid ? fh * acc[t][g] + fh : -1e30f;  // (corr+1)*0.5*fit
      acc[t][g] = val;
      mx = fmaxf(mx, val);
    }
  }
  mx = fmaxf(mx, __shfl_xor(mx, 16));
  mx = fmaxf(mx, __shfl_xor(mx, 32));
  #pragma unroll
  for (int t = 0; t < NT; ++t) {
    if (t < wv || t > wv + 8) continue;
    #pragma unroll
    for (int g = 0; g < 4; ++g) {
      float e = __expf(acc[t][g] - mx);      // masked -> 0
      acc[t][g] = e;
      esum += e;
    }
  }
  esum += __shfl_xor(esum, 16);
  esum += __shfl_xor(esum, 32);
  const float rinv = 1.0f / esum;

  // ---- band cover stores: f32x4 chunks within [jlo, jhi] (uint4-aligned) --
  const int jlo = (i_g >= WIN) ? ((i_g - WIN) & ~3) : 0;
  const int jhi = (i_g & ~3) + 3;
  float* outrow = out + ((size_t)bh * T_DIM + i_g) * T_DIM;
  #pragma unroll
  for (int t = 0; t < NT; ++t) {
    if (t < wv || t > wv + 8) continue;
    int jb = base - WIN + t * 16 + kg * 4;   // 4-aligned global j of chunk
    if (jb >= jlo && jb + 3 <= jhi) {
      f32x4 val = {acc[t][0] * rinv, acc[t][1] * rinv,
                   acc[t][2] * rinv, acc[t][3] * rinv};
      __builtin_nontemporal_store(val, (f32x4*)(outrow + jb));
    }
  }

  // ---- zero pass LAST: fire-and-forget, drains only at kernel end ---------
  {
    const f32x4 z = {0.f, 0.f, 0.f, 0.f};
    f32x4* outq = (f32x4*)out + ((size_t)bh * T_DIM + base) * (T_DIM / 4);
    const int q = tid;
    #pragma unroll 4
    for (int r = 0; r < TILE; ++r) {
      int i = base + r;
      int q0 = (i >= WIN) ? ((i - WIN) >> 2) : 0;
      int q1 = i >> 2;
      if (q < q0 || q > q1)
        __builtin_nontemporal_store(z, &outq[r * (T_DIM / 4) + q]);
    }
  }
}

extern "C" void kernel_launch(void* const* d_in, const int* in_sizes, int n_in,
                              void* d_out, int out_size, void* d_ws, size_t ws_size,
                              hipStream_t stream) {
  const float* E = (const float*)d_in[0];
  float* out = (float*)d_out;
  float* partials = (float*)d_ws;                        // 512 floats
  unsigned int* flags = (unsigned int*)(partials + NBLK); // 512 uints
  hipLaunchKernelGGL(fused_kernel, dim3(NBLK), dim3(NTHR), 0, stream,
                     E, out, partials, flags);
}

// Round 13
// 154.549 us; speedup vs baseline: 1.4599x; 1.1215x over previous
//
#include <hip/hip_runtime.h>

#define T_DIM 1024
#define D_DIM 64
#define WIN   128
#define TILE  64       // output rows per block
#define KROWS 192      // staged rows = TILE + WIN
#define NT    12       // KROWS/16 col-tiles
#define NTHR  256      // 4 waves
#define NBLK  512      // 32 (b,h) * 16 tiles = 2 blocks/CU exactly (co-resident)
#define NBH   32

typedef __attribute__((ext_vector_type(8))) short short8;
typedef __attribute__((ext_vector_type(4))) float f32x4;

__device__ __forceinline__ unsigned int pack2bf(float a, float b) {
  unsigned int ua = __float_as_uint(a);
  unsigned int ub = __float_as_uint(b);
  ua = (ua + 0x7fffu + ((ua >> 16) & 1u)) >> 16;   // RNE f32->bf16
  ub = (ub + 0x7fffu + ((ub >> 16) & 1u)) >> 16;
  return ua | (ub << 16);
}

// ---------------------------------------------------------------------------
// Fused: stage U once, EARLY fire-and-forget zero stores (drain under all
// later phases), MFMA once, fence-free 16-block sync via packed 64-bit
// relaxed atomics (flag+payload in one word -> no release -> no store drain),
// softmax on retained accumulators, band f32x4 stores.
// ---------------------------------------------------------------------------
__global__ __launch_bounds__(NTHR, 2)
void fused_kernel(const float* __restrict__ E, float* __restrict__ out,
                  unsigned long long* __restrict__ words)
{
  __shared__ uint4 Kb4[KROWS * 8];           // 24 KB, swizzled 16B units
  __shared__ float wpart[4];
  __shared__ float s_rsum;

  const int tid = threadIdx.x, lane = tid & 63, wv = tid >> 6;
  const int blk = blockIdx.x, bh = blk >> 4, base = (blk & 15) * TILE;
  const float* Ebh = E + (size_t)bh * (T_DIM * D_DIM);

  // ---- stage rows [base-128, base+63] normalized (U=E/|E|) bf16, swizzled --
  #pragma unroll
  for (int it = 0; it < (KROWS * 8) / NTHR; ++it) {   // 6 iters
    int u = tid + it * NTHR;
    int r = u >> 3, c = u & 7;
    int gr = base - WIN + r;
    uint4 w = make_uint4(0u, 0u, 0u, 0u);
    if (gr >= 0) {
      const float4 f0 = *(const float4*)(Ebh + gr * D_DIM + c * 8);
      const float4 f1 = *(const float4*)(Ebh + gr * D_DIM + c * 8 + 4);
      float ss = f0.x*f0.x + f0.y*f0.y + f0.z*f0.z + f0.w*f0.w
               + f1.x*f1.x + f1.y*f1.y + f1.z*f1.z + f1.w*f1.w;
      ss += __shfl_xor(ss, 1);
      ss += __shfl_xor(ss, 2);
      ss += __shfl_xor(ss, 4);
      float rn = rsqrtf(ss + 1e-16f);
      w.x = pack2bf(f0.x*rn, f0.y*rn); w.y = pack2bf(f0.z*rn, f0.w*rn);
      w.z = pack2bf(f1.x*rn, f1.y*rn); w.w = pack2bf(f1.z*rn, f1.w*rn);
    }
    Kb4[(r << 3) + (c ^ (r & 7))] = w;
  }
  __syncthreads();

  // ---- EARLY zero pass: fire-and-forget; pinned here by compiler barriers -
  asm volatile("" ::: "memory");
  {
    const f32x4 z = {0.f, 0.f, 0.f, 0.f};
    f32x4* outq = (f32x4*)out + ((size_t)bh * T_DIM + base) * (T_DIM / 4);
    const int q = tid;
    #pragma unroll 4
    for (int r = 0; r < TILE; ++r) {
      int i = base + r;
      int q0 = (i >= WIN) ? ((i - WIN) >> 2) : 0;
      int q1 = i >> 2;
      if (q < q0 || q > q1)
        __builtin_nontemporal_store(z, &outq[r * (T_DIM / 4) + q]);
    }
  }
  asm volatile("" ::: "memory");

  // ---- MFMA: swapped operands (D = K.Q^T) -> lane holds 4 consecutive j ---
  const short8* KbF = (const short8*)Kb4;
  const int mrow = lane & 15, kg = lane >> 4;
  const int i_local = wv * 16 + mrow;
  const int i_g = base + i_local;

  const int qr = WIN + i_local;              // Q fragment (D cols = i)
  short8 b0 = KbF[(qr << 3) + (kg ^ (qr & 7))];
  short8 b1 = KbF[(qr << 3) + ((kg + 4) ^ (qr & 7))];

  f32x4 acc[NT];
  float sacc = 0.f;
  #pragma unroll
  for (int t = 0; t < NT; ++t) {
    if (t < wv || t > wv + 8) continue;      // no valid (i,j) outside
    int br = t * 16 + mrow;                  // K rows (D rows = j)
    short8 a0 = KbF[(br << 3) + (kg ^ (br & 7))];
    short8 a1 = KbF[(br << 3) + ((kg + 4) ^ (br & 7))];
    f32x4 ca = {0.f, 0.f, 0.f, 0.f};
    ca = __builtin_amdgcn_mfma_f32_16x16x32_bf16(a0, b0, ca, 0, 0, 0);
    ca = __builtin_amdgcn_mfma_f32_16x16x32_bf16(a1, b1, ca, 0, 0, 0);
    acc[t] = ca;                             // reg g: rj = t*16+kg*4+g, col i
    #pragma unroll
    for (int g = 0; g < 4; ++g) {
      int rj = t * 16 + kg * 4 + g;
      bool valid = (rj >= i_local) && (rj <= i_local + WIN)
                && (base - WIN + rj >= 0);
      sacc += valid ? ca[g] : 0.f;
    }
  }
  sacc += __shfl_xor(sacc, 16);
  sacc += __shfl_xor(sacc, 32);              // S_i in all lanes
  const float invden = 2048.f / (2048.f + sacc);      // 1/denom (2T = 2048)

  // ---- publish per-block partial: flag+payload in ONE relaxed 64-bit word -
  float v = (kg == 0) ? invden : 0.f;        // one contribution per row
  #pragma unroll
  for (int m = 1; m < 64; m <<= 1) v += __shfl_xor(v, m);
  if (lane == 0) wpart[wv] = v;
  __syncthreads();
  if (tid == 0) {
    float psum = wpart[0] + wpart[1] + wpart[2] + wpart[3];
    unsigned long long w = (1ull << 32) |
                           (unsigned long long)__float_as_uint(psum);
    __hip_atomic_store(&words[blk], w, __ATOMIC_RELAXED,
                       __HIP_MEMORY_SCOPE_AGENT);
  }

  // ---- 16-block sync: poll sibling words (co-resident; no fences) ---------
  if (tid < 16) {
    const int sib = (bh << 4) + tid;
    unsigned long long w;
    while (((w = __hip_atomic_load(&words[sib], __ATOMIC_RELAXED,
                                   __HIP_MEMORY_SCOPE_AGENT)) >> 32) != 1ull)
      __builtin_amdgcn_s_sleep(2);
    float p = __uint_as_float((unsigned int)w);
    #pragma unroll
    for (int m = 1; m < 16; m <<= 1) p += __shfl_xor(p, m);
    if (tid == 0) s_rsum = 1.0f / p;
  }
  __syncthreads();

  const float fh = 0.5f * invden * s_rsum;   // 0.5 * fitness_i

  // ---- masked value + in-register softmax (reduce over kg: 2 shfls) -------
  float mx = -1e30f, esum = 0.f;
  #pragma unroll
  for (int t = 0; t < NT; ++t) {
    if (t < wv || t > wv + 8) continue;
    #pragma unroll
    for (int g = 0; g < 4; ++g) {
      int rj = t * 16 + kg * 4 + g;
      bool valid = (rj >= i_local) && (rj <= i_local + WIN)
                && (base - WIN + rj >= 0);
      float val = valid ? fh * acc[t][g] + fh : -1e30f;  // (corr+1)*0.5*fit
      acc[t][g] = val;
      mx = fmaxf(mx, val);
    }
  }
  mx = fmaxf(mx, __shfl_xor(mx, 16));
  mx = fmaxf(mx, __shfl_xor(mx, 32));
  #pragma unroll
  for (int t = 0; t < NT; ++t) {
    if (t < wv || t > wv + 8) continue;
    #pragma unroll
    for (int g = 0; g < 4; ++g) {
      float e = __expf(acc[t][g] - mx);      // masked -> 0
      acc[t][g] = e;
      esum += e;
    }
  }
  esum += __shfl_xor(esum, 16);
  esum += __shfl_xor(esum, 32);
  const float rinv = 1.0f / esum;

  // ---- band cover stores: f32x4 chunks within [jlo, jhi] (uint4-aligned) --
  const int jlo = (i_g >= WIN) ? ((i_g - WIN) & ~3) : 0;
  const int jhi = (i_g & ~3) + 3;
  float* outrow = out + ((size_t)bh * T_DIM + i_g) * T_DIM;
  #pragma unroll
  for (int t = 0; t < NT; ++t) {
    if (t < wv || t > wv + 8) continue;
    int jb = base - WIN + t * 16 + kg * 4;   // 4-aligned global j of chunk
    if (jb >= jlo && jb + 3 <= jhi) {
      f32x4 val = {acc[t][0] * rinv, acc[t][1] * rinv,
                   acc[t][2] * rinv, acc[t][3] * rinv};
      __builtin_nontemporal_store(val, (f32x4*)(outrow + jb));
    }
  }
}

extern "C" void kernel_launch(void* const* d_in, const int* in_sizes, int n_in,
                              void* d_out, int out_size, void* d_ws, size_t ws_size,
                              hipStream_t stream) {
  const float* E = (const float*)d_in[0];
  float* out = (float*)d_out;
  unsigned long long* words = (unsigned long long*)d_ws;   // 512 x 8B
  hipLaunchKernelGGL(fused_kernel, dim3(NBLK), dim3(NTHR), 0, stream,
                     E, out, words);
}